// Round 1
// baseline (7390.887 us; speedup 1.0000x reference)
//
#include <hip/hip_runtime.h>

#define BS 512

// ---- LDS float offsets (weights transposed [o][i], row stride 44, block stride 3524) ----
#define ROWSTR 44
#define BLKSTR 3524   // 80*44 + 4  -> branch bases land in banks 0,4,8,12

#define OFF_W0 0        // 240   [c*40+o]
#define OFF_B0 240      // 40
#define OFF_W1 280      // 3520  [o][i] o in [0,80)
#define OFF_B1 3800     // 80
#define OFF_W2 3880     // 7048  block h at +h*BLKSTR, [oc][i] oc in [0,80)
#define OFF_B2 10928    // 160
#define OFF_W3 11088    // 14096 block g at +g*BLKSTR
#define OFF_B3 25184    // 320
#define OFF_W4 25504    // 320
#define OFF_B4 25824    // 4
#define OFF_CZ0 25828   // 128 rows * 44
#define OFF_RED 31460   // 8
#define SM_TOT 31472    // floats = 125,888 B

#define PI_F 3.14159265358979f

// res += dot(w_row[0:40], X[0:40]) with 4 partial accumulators (chain depth 10)
#define DOT40(res, wbase, X) do { \
  float a0_=0.f,a1_=0.f,a2_=0.f,a3_=0.f; \
  const float* wp_ = (wbase); \
  _Pragma("unroll") \
  for (int i_=0;i_<40;i_+=4){ const float4 w_ = *(const float4*)(wp_+i_); \
    a0_ += (X)[i_]*w_.x; a1_ += (X)[i_+1]*w_.y; a2_ += (X)[i_+2]*w_.z; a3_ += (X)[i_+3]*w_.w; } \
  res += (a0_+a1_)+(a2_+a3_); } while(0)

// ACC[i] += t * w_row[i]
#define AXPY40(ACC, wbase, tt) do { \
  const float t_ = (tt); \
  const float* wp_ = (wbase); \
  _Pragma("unroll") \
  for (int i_=0;i_<40;i_+=4){ const float4 w_ = *(const float4*)(wp_+i_); \
    ACC[i_] += t_*w_.x; ACC[i_+1] += t_*w_.y; ACC[i_+2] += t_*w_.z; ACC[i_+3] += t_*w_.w; } } while(0)

template<bool BND>
__global__ __launch_bounds__(512, 2)
void net_integral(const float* __restrict__ xi_coord, const float* __restrict__ xi_wts,
                  const float* __restrict__ xb_coord, const float* __restrict__ xb_wts,
                  const float* __restrict__ xb_normal, const float* __restrict__ z_coord,
                  const float* __restrict__ W0, const float* __restrict__ b0,
                  const float* __restrict__ W1, const float* __restrict__ b1,
                  const float* __restrict__ W2, const float* __restrict__ b2,
                  const float* __restrict__ W3, const float* __restrict__ b3,
                  const float* __restrict__ W4, const float* __restrict__ b4,
                  const int* __restrict__ xb_btype, const int* __restrict__ case_index,
                  float* __restrict__ out)
{
  __shared__ float sm[SM_TOT];
  const int tid = threadIdx.x;

  // ---- stage weights to LDS (transposed + padded) ----
  for (int idx = tid; idx < 240; idx += BS) sm[OFF_W0+idx] = W0[idx];
  for (int idx = tid; idx < 40;  idx += BS) sm[OFF_B0+idx] = b0[idx];
  for (int idx = tid; idx < 3200; idx += BS){
    const int o = idx/40, i = idx - o*40;
    sm[OFF_W1 + o*ROWSTR + i] = W1[i*80 + o];
  }
  for (int idx = tid; idx < 80;  idx += BS) sm[OFF_B1+idx] = b1[idx];
  for (int idx = tid; idx < 6400; idx += BS){
    const int h = idx/3200; const int r = idx - h*3200;
    const int o = r/40, i = r - o*40;
    sm[OFF_W2 + h*BLKSTR + o*ROWSTR + i] = W2[(40*h + i)*160 + 80*h + o];
  }
  for (int idx = tid; idx < 160; idx += BS) sm[OFF_B2+idx] = b2[idx];
  for (int idx = tid; idx < 12800; idx += BS){
    const int gb = idx/3200; const int r = idx - gb*3200;
    const int o = r/40, i = r - o*40;
    sm[OFF_W3 + gb*BLKSTR + o*ROWSTR + i] = W3[(40*gb + i)*320 + 80*gb + o];
  }
  for (int idx = tid; idx < 320; idx += BS) sm[OFF_B3+idx] = b3[idx];
  for (int idx = tid; idx < 320; idx += BS) sm[OFF_W4+idx] = W4[idx];
  if (tid == 0) sm[OFF_B4] = b4[0];
  __syncthreads();

  const float cval = (float)(case_index[0] + 1);
  const int g   = tid & 3;     // layer-3 branch owned by this lane
  const int h   = g >> 1;      // layer-2 block / X1 half
  const int sub = g & 1;       // quarter within layer-2 block
  const int rl  = tid >> 2;    // row (pair) within block, 128 rows

  for (int bid = blockIdx.x; bid < 2048; bid += 256) {
    const int z = bid >> 2;
    const int p = ((bid & 3) << 7) + rl;   // x-index (interior) or b-index (boundary)

    const float* xc = BND ? xb_coord : xi_coord;
    const float in0 = xc[p*3+0], in1 = xc[p*3+1], in2 = xc[p*3+2];
    const float in3 = z_coord[z*3+0], in4 = z_coord[z*3+1], in5 = z_coord[z*3+2];

    // ---- P1: layer 0 (6 -> 40), all lanes redundant ----
    float X0[40];
    #pragma unroll
    for (int o=0;o<40;o++){
      float a = sm[OFF_B0+o]
        + in0*sm[OFF_W0+o]       + in1*sm[OFF_W0+40+o]  + in2*sm[OFF_W0+80+o]
        + in3*sm[OFF_W0+120+o]   + in4*sm[OFF_W0+160+o] + in5*sm[OFF_W0+200+o];
      X0[o] = __sinf(a);
      if (BND) {
        if (g == (o/10)) sm[OFF_CZ0 + rl*ROWSTR + o] = __cosf(a);  // each lane writes its 10
      }
    }
    if (BND) __syncthreads();   // make CZ0 visible across the 4-lane group

    // ---- P2: layer 1 half h (40 -> 40 of 80) ----
    float X1h[40], cZ1[40];
    #pragma unroll
    for (int o=0;o<40;o++){
      const int og = 40*h + o;
      float a = sm[OFF_B1+og];
      DOT40(a, &sm[OFF_W1 + og*ROWSTR], X0);
      X1h[o] = __sinf(a);
      if (BND) cZ1[o] = __cosf(a);
    }

    // ---- P3: layer 2 quarter (40 -> 40 of 160) ----
    float X2q[40], cZ2[40];
    #pragma unroll
    for (int o=0;o<40;o++){
      const int oc = 40*sub + o;
      float a = sm[OFF_B2 + 80*h + oc];
      DOT40(a, &sm[OFF_W2 + h*BLKSTR + oc*ROWSTR], X1h);
      X2q[o] = __sinf(a);
      if (BND) cZ2[o] = __cosf(a);
    }

    // ---- P4: layer 3 block g (40 -> 80) + output dot (fwd) / dX2 (bwd) ----
    float dX2[40];
    if (BND) {
      #pragma unroll
      for (int i=0;i<40;i++) dX2[i] = 0.f;
    }
    float Gpart = 0.f;
    #pragma unroll
    for (int o=0;o<80;o++){
      const float* wr = &sm[OFF_W3 + g*BLKSTR + o*ROWSTR];
      float a = sm[OFF_B3 + 80*g + o];
      DOT40(a, wr, X2q);
      const float w4 = sm[OFF_W4 + 80*g + o];
      if (!BND) {
        Gpart += __sinf(a) * w4;
      } else {
        AXPY40(dX2, wr, __cosf(a) * w4);   // dZ3 = W4 * cos(Z3), push through W3^T
      }
    }

    float val;
    if (!BND) {
      float G = Gpart + __shfl_xor(Gpart, 1);
      G += __shfl_xor(G, 2);
      G += sm[OFF_B4];
      const float fx = __sinf(PI_F*cval*in0) * __sinf(PI_F*in1) * __sinf(PI_F*in2);
      val = (g == 0) ? G * fx * xi_wts[p] : 0.f;
    } else {
      // ---- P5: backward through layer 2 ----
      #pragma unroll
      for (int i=0;i<40;i++) dX2[i] *= cZ2[i];          // dZ2 (quarter)
      float dX1[40];
      #pragma unroll
      for (int i=0;i<40;i++) dX1[i] = 0.f;
      #pragma unroll
      for (int o=0;o<40;o++){
        const int oc = 40*sub + o;
        AXPY40(dX1, &sm[OFF_W2 + h*BLKSTR + oc*ROWSTR], dX2[o]);
      }
      #pragma unroll
      for (int i=0;i<40;i++){
        dX1[i] += __shfl_xor(dX1[i], 1);                // merge sibling quarter
        dX1[i] *= cZ1[i];                               // dZ1 (half h)
      }
      // ---- P6: backward through layer 1 ----
      float dX0[40];
      #pragma unroll
      for (int i=0;i<40;i++) dX0[i] = 0.f;
      #pragma unroll
      for (int o=0;o<40;o++){
        AXPY40(dX0, &sm[OFF_W1 + (40*h + o)*ROWSTR], dX1[o]);
      }
      // ---- P7: merge halves, through layer 0 to x-gradient ----
      float dx0=0.f, dx1=0.f, dx2=0.f;
      #pragma unroll
      for (int i=0;i<40;i++){
        const float s = dX0[i] + __shfl_xor(dX0[i], 2); // both halves
        const float e = s * sm[OFF_CZ0 + rl*ROWSTR + i]; // dZ0
        dx0 += e * sm[OFF_W0 + i];
        dx1 += e * sm[OFF_W0 + 40 + i];
        dx2 += e * sm[OFF_W0 + 80 + i];
      }
      const float n0 = xb_normal[p*3+0], n1 = xb_normal[p*3+1], n2 = xb_normal[p*3+2];
      const float gn = dx0*n0 + dx1*n1 + dx2*n2;
      const float gb = __sinf(cval*(in0+in1+in2)) * (1.f + 0.1f*(float)xb_btype[p]);
      const float ab = 1.f + 0.5f*__cosf(in0);
      val = (g == 0) ? gn * ab * gb * xb_wts[p] : 0.f;
    }

    // ---- block reduction -> atomic ----
    #pragma unroll
    for (int off = 32; off > 0; off >>= 1) val += __shfl_down(val, off);
    const int wid = tid >> 6;
    if ((tid & 63) == 0) sm[OFF_RED + wid] = val;
    __syncthreads();
    if (tid == 0){
      float s = 0.f;
      #pragma unroll
      for (int w = 0; w < 8; w++) s += sm[OFF_RED + w];
      atomicAdd(out + z, BND ? -s : s);
    }
    __syncthreads();   // protect RED / CZ0 for next tile
  }
}

extern "C" void kernel_launch(void* const* d_in, const int* in_sizes, int n_in,
                              void* d_out, int out_size, void* d_ws, size_t ws_size,
                              hipStream_t stream) {
  const float* xi_coord  = (const float*)d_in[0];
  const float* xi_wts    = (const float*)d_in[1];
  const float* xb_coord  = (const float*)d_in[2];
  const float* xb_wts    = (const float*)d_in[3];
  const float* xb_normal = (const float*)d_in[4];
  const float* z_coord   = (const float*)d_in[5];
  const float* W0 = (const float*)d_in[6];
  const float* b0 = (const float*)d_in[7];
  const float* W1 = (const float*)d_in[8];
  const float* b1 = (const float*)d_in[9];
  const float* W2 = (const float*)d_in[10];
  const float* b2 = (const float*)d_in[11];
  const float* W3 = (const float*)d_in[12];
  const float* b3 = (const float*)d_in[13];
  const float* W4 = (const float*)d_in[14];
  const float* b4 = (const float*)d_in[15];
  const int* xb_btype   = (const int*)d_in[16];
  const int* case_index = (const int*)d_in[17];
  float* out = (float*)d_out;

  hipMemsetAsync(d_out, 0, (size_t)out_size * sizeof(float), stream);

  dim3 grid(256), blk(BS);
  hipLaunchKernelGGL((net_integral<false>), grid, blk, 0, stream,
      xi_coord, xi_wts, xb_coord, xb_wts, xb_normal, z_coord,
      W0, b0, W1, b1, W2, b2, W3, b3, W4, b4, xb_btype, case_index, out);
  hipLaunchKernelGGL((net_integral<true>), grid, blk, 0, stream,
      xi_coord, xi_wts, xb_coord, xb_wts, xb_normal, z_coord,
      W0, b0, W1, b1, W2, b2, W3, b3, W4, b4, xb_btype, case_index, out);
}

// Round 2
// 3321.717 us; speedup vs baseline: 2.2250x; 2.2250x over previous
//
#include <hip/hip_runtime.h>

#define PI_F 3.14159265358979f

// LDS float layout: z0[40][64] | Z1[80][64] | red[8]
#define LZ0(i,pt)  ((i)*64 + (pt))
#define LZ1(c,pt)  (2560 + (c)*64 + (pt))
#define LRED       (2560 + 5120)
#define LDS_FLOATS (2560 + 5120 + 8)

// One wave per layer-3 branch (g = wave id, uniform via readfirstlane so all
// weight indices are scalar -> s_load), one lane per point. Trunk (Z0, Z1)
// shared across waves through LDS; per-branch state in registers with
// fully-unrolled constant indexing. Peak ~135 VGPR -> 3 waves/SIMD.
template<bool BND>
__global__ __attribute__((amdgpu_flat_work_group_size(256,256), amdgpu_waves_per_eu(3,4)))
void net_integral(const float* __restrict__ xi_coord, const float* __restrict__ xi_wts,
                  const float* __restrict__ xb_coord, const float* __restrict__ xb_wts,
                  const float* __restrict__ xb_normal, const float* __restrict__ z_coord,
                  const float* __restrict__ W0, const float* __restrict__ b0,
                  const float* __restrict__ W1, const float* __restrict__ b1,
                  const float* __restrict__ W2, const float* __restrict__ b2,
                  const float* __restrict__ W3, const float* __restrict__ b3,
                  const float* __restrict__ W4, const float* __restrict__ b4,
                  const int* __restrict__ xb_btype, const int* __restrict__ case_index,
                  float* __restrict__ out)
{
  __shared__ float sm[LDS_FLOATS];
  const int tid  = threadIdx.x;
  const int lane = tid & 63;
  // wave index made provably uniform -> all derived weight indices are scalar
  const int w   = __builtin_amdgcn_readfirstlane(tid >> 6);
  const int g   = w;            // layer-3 branch (0..3)
  const int h   = w >> 1;       // layer-2 block / X1 half
  const int sub = w & 1;        // quarter within layer-2 block
  const int c2b = 80*h + 40*sub;   // layer-2 col base (== 40*g)

  const float cval = (float)(case_index[0] + 1);

  for (int s = blockIdx.x; s < 4096; s += gridDim.x) {
    const int z = s >> 3;
    const int p = ((s & 7) << 6) + lane;

    const float* xc = BND ? xb_coord : xi_coord;
    const float in0 = xc[p*3+0], in1 = xc[p*3+1], in2 = xc[p*3+2];
    const float zc0 = z_coord[z*3+0], zc1 = z_coord[z*3+1], zc2 = z_coord[z*3+2];

    __syncthreads();   // protect z0/Z1/red from previous iteration

    // ---- stage A: Z0 (pre-activation), cooperative: wave w -> outputs [10w,10w+10) ----
    {
      const int ob = 10*w;
      #pragma unroll
      for (int k=0;k<10;k++) {
        float a = b0[ob+k]
          + in0*W0[0*40+ob+k] + in1*W0[1*40+ob+k] + in2*W0[2*40+ob+k]
          + zc0*W0[3*40+ob+k] + zc1*W0[4*40+ob+k] + zc2*W0[5*40+ob+k];
        sm[LZ0(ob+k, lane)] = a;
      }
    }
    __syncthreads();

    // ---- stage B: Z1 (pre-activation), cooperative: wave w -> flat cols [20w,20w+20) ----
    {
      const int c0 = 20*w;
      float acc[20];
      #pragma unroll
      for (int k=0;k<20;k++) acc[k] = b1[c0+k];
      for (int i=0;i<40;i++) {
        const float x0 = __sinf(sm[LZ0(i,lane)]);
        #pragma unroll
        for (int k=0;k<20;k++) acc[k] += x0 * W1[i*80 + c0 + k];
      }
      #pragma unroll
      for (int k=0;k<20;k++) sm[LZ1(c0+k, lane)] = acc[k];
    }
    __syncthreads();

    // ---- stage C: private branch pipeline (wave g) ----
    // L2 forward: z2[40] = pre-activation of branch input quarter
    float z2[40];
    #pragma unroll
    for (int o=0;o<40;o++) z2[o] = b2[c2b+o];
    for (int i=0;i<40;i++) {
      const float x1 = __sinf(sm[LZ1(40*h+i, lane)]);
      #pragma unroll
      for (int o=0;o<40;o++) z2[o] += x1 * W2[(40*h+i)*160 + c2b + o];
    }

    // L3 forward: z3[80] pre-activation (fully unrolled: constant reg indices)
    float z3[80];
    #pragma unroll
    for (int o=0;o<80;o++) z3[o] = b3[80*g+o];
    #pragma unroll
    for (int i=0;i<40;i++) {
      const float x2 = __sinf(z2[i]);
      const float* wr = &W3[(40*g+i)*320 + 80*g];
      #pragma unroll
      for (int o=0;o<80;o++) z3[o] += x2 * wr[o];
    }

    float val;
    if (!BND) {
      float Gp = (w==0) ? b4[0] : 0.f;
      #pragma unroll
      for (int o=0;o<80;o++) Gp += __sinf(z3[o]) * W4[80*g+o];
      const float fx = __sinf(PI_F*cval*in0) * __sinf(PI_F*in1) * __sinf(PI_F*in2);
      val = Gp * fx * xi_wts[p];
    } else {
      // dZ3 = cos(Z3) * W4  (in place)
      #pragma unroll
      for (int o=0;o<80;o++) z3[o] = __cosf(z3[o]) * W4[80*g+o];
      // L3 backward: z2 <- dZ2 = (W3_g^T dZ3) .* cos(Z2)
      #pragma unroll
      for (int i=0;i<40;i++) {
        const float* wr = &W3[(40*g+i)*320 + 80*g];
        float a0=0.f,a1=0.f,a2=0.f,a3=0.f;
        #pragma unroll
        for (int o=0;o<80;o+=4) {
          a0 += z3[o+0]*wr[o+0]; a1 += z3[o+1]*wr[o+1];
          a2 += z3[o+2]*wr[o+2]; a3 += z3[o+3]*wr[o+3];
        }
        z2[i] = ((a0+a1)+(a2+a3)) * __cosf(z2[i]);
      }
      // L2 backward: dz1[40] = (W2_blk^T dZ2) .* cos(Z1 half)
      float dz1[40];
      #pragma unroll
      for (int i=0;i<40;i++) {
        const float* wr = &W2[(40*h+i)*160 + c2b];
        float a0=0.f,a1=0.f,a2=0.f,a3=0.f;
        #pragma unroll
        for (int o=0;o<40;o+=4) {
          a0 += z2[o+0]*wr[o+0]; a1 += z2[o+1]*wr[o+1];
          a2 += z2[o+2]*wr[o+2]; a3 += z2[o+3]*wr[o+3];
        }
        dz1[i] = ((a0+a1)+(a2+a3)) * __cosf(sm[LZ1(40*h+i, lane)]);
      }
      // L1 backward + fold to x-gradient (rolled j: no runtime reg-array indexing)
      float dx0=0.f, dx1=0.f, dx2=0.f;
      for (int j=0;j<40;j++) {
        const float* wr = &W1[j*80 + 40*h];
        float a0=0.f,a1=0.f,a2=0.f,a3=0.f;
        #pragma unroll
        for (int i=0;i<40;i+=4) {
          a0 += dz1[i+0]*wr[i+0]; a1 += dz1[i+1]*wr[i+1];
          a2 += dz1[i+2]*wr[i+2]; a3 += dz1[i+3]*wr[i+3];
        }
        const float e = ((a0+a1)+(a2+a3)) * __cosf(sm[LZ0(j, lane)]);
        dx0 += e * W0[0*40+j];
        dx1 += e * W0[1*40+j];
        dx2 += e * W0[2*40+j];
      }
      const float n0 = xb_normal[p*3+0], n1 = xb_normal[p*3+1], n2 = xb_normal[p*3+2];
      const float gn = dx0*n0 + dx1*n1 + dx2*n2;
      const float gb = __sinf(cval*(in0+in1+in2)) * (1.f + 0.1f*(float)xb_btype[p]);
      const float ab = 1.f + 0.5f*__cosf(in0);
      val = gn * ab * gb * xb_wts[p];
    }

    // ---- reduce 256 lanes -> 1 atomic per set ----
    #pragma unroll
    for (int off=32; off>0; off>>=1) val += __shfl_down(val, off);
    if (lane==0) sm[LRED + w] = val;
    __syncthreads();
    if (tid==0) {
      const float ssum = sm[LRED+0]+sm[LRED+1]+sm[LRED+2]+sm[LRED+3];
      atomicAdd(out + z, BND ? -ssum : ssum);
    }
  }
}

extern "C" void kernel_launch(void* const* d_in, const int* in_sizes, int n_in,
                              void* d_out, int out_size, void* d_ws, size_t ws_size,
                              hipStream_t stream) {
  const float* xi_coord  = (const float*)d_in[0];
  const float* xi_wts    = (const float*)d_in[1];
  const float* xb_coord  = (const float*)d_in[2];
  const float* xb_wts    = (const float*)d_in[3];
  const float* xb_normal = (const float*)d_in[4];
  const float* z_coord   = (const float*)d_in[5];
  const float* W0 = (const float*)d_in[6];
  const float* b0 = (const float*)d_in[7];
  const float* W1 = (const float*)d_in[8];
  const float* b1 = (const float*)d_in[9];
  const float* W2 = (const float*)d_in[10];
  const float* b2 = (const float*)d_in[11];
  const float* W3 = (const float*)d_in[12];
  const float* b3 = (const float*)d_in[13];
  const float* W4 = (const float*)d_in[14];
  const float* b4 = (const float*)d_in[15];
  const int* xb_btype   = (const int*)d_in[16];
  const int* case_index = (const int*)d_in[17];
  float* out = (float*)d_out;

  hipMemsetAsync(d_out, 0, (size_t)out_size * sizeof(float), stream);

  dim3 grid(1024), blk(256);
  hipLaunchKernelGGL((net_integral<false>), grid, blk, 0, stream,
      xi_coord, xi_wts, xb_coord, xb_wts, xb_normal, z_coord,
      W0, b0, W1, b1, W2, b2, W3, b3, W4, b4, xb_btype, case_index, out);
  hipLaunchKernelGGL((net_integral<true>), grid, blk, 0, stream,
      xi_coord, xi_wts, xb_coord, xb_wts, xb_normal, z_coord,
      W0, b0, W1, b1, W2, b2, W3, b3, W4, b4, xb_btype, case_index, out);
}

// Round 3
// 984.247 us; speedup vs baseline: 7.5092x; 3.3749x over previous
//
#include <hip/hip_runtime.h>

#define PI_F 3.14159265358979f

// LDS float layout: Z0[40][64] | Z1[80][64] | red[4]
#define LZ0(i,pt)  ((i)*64 + (pt))
#define LZ1(c,pt)  (2560 + (c)*64 + (pt))
#define LRED       (2560 + 5120)
#define LDS_FLOATS (2560 + 5120 + 4)

// One wave per layer-3 branch (g = wave id, uniform via readfirstlane so all
// weight indices are scalar -> s_load), one lane per point, one point-set per
// block. Trunk (Z0, Z1) shared across the 4 waves through LDS. Layer 3 is
// walked COLUMN-wise so the 80-deep pre-activation array never materializes:
// peak live ~120 floats (z2 + s2 + dZ2acc), no spill.
template<bool BND>
__global__ __launch_bounds__(256)
void net_integral(const float* __restrict__ xi_coord, const float* __restrict__ xi_wts,
                  const float* __restrict__ xb_coord, const float* __restrict__ xb_wts,
                  const float* __restrict__ xb_normal, const float* __restrict__ z_coord,
                  const float* __restrict__ W0, const float* __restrict__ b0,
                  const float* __restrict__ W1, const float* __restrict__ b1,
                  const float* __restrict__ W2, const float* __restrict__ b2,
                  const float* __restrict__ W3, const float* __restrict__ b3,
                  const float* __restrict__ W4, const float* __restrict__ b4,
                  const int* __restrict__ xb_btype, const int* __restrict__ case_index,
                  float* __restrict__ out)
{
  __shared__ float sm[LDS_FLOATS];
  const int tid  = threadIdx.x;
  const int lane = tid & 63;
  const int w   = __builtin_amdgcn_readfirstlane(tid >> 6);
  const int g   = w;            // layer-3 branch (0..3)
  const int h   = w >> 1;       // layer-2 block / X1 half
  const int c2b = 40*g;         // layer-2 col base (80*h + 40*(w&1) == 40*g)

  const float cval = (float)(case_index[0] + 1);

  const int s = blockIdx.x;          // 4096 point-sets
  const int z = s >> 3;
  const int p = ((s & 7) << 6) + lane;

  const float* xc = BND ? xb_coord : xi_coord;
  const float in0 = xc[p*3+0], in1 = xc[p*3+1], in2 = xc[p*3+2];
  const float zc0 = z_coord[z*3+0], zc1 = z_coord[z*3+1], zc2 = z_coord[z*3+2];

  // ---- stage A: Z0 pre-activation, wave w -> outputs [10w, 10w+10) ----
  {
    const int ob = 10*w;
    #pragma unroll
    for (int k=0;k<10;k++) {
      float a = b0[ob+k]
        + in0*W0[0*40+ob+k] + in1*W0[1*40+ob+k] + in2*W0[2*40+ob+k]
        + zc0*W0[3*40+ob+k] + zc1*W0[4*40+ob+k] + zc2*W0[5*40+ob+k];
      sm[LZ0(ob+k, lane)] = a;
    }
  }
  __syncthreads();

  // ---- stage B: Z1 pre-activation, wave w -> flat cols [20w, 20w+20) ----
  {
    const int c0 = 20*w;
    float acc[20];
    #pragma unroll
    for (int k=0;k<20;k++) acc[k] = b1[c0+k];
    for (int i=0;i<40;i++) {
      const float x0 = __sinf(sm[LZ0(i,lane)]);
      #pragma unroll
      for (int k=0;k<20;k++) acc[k] += x0 * W1[i*80 + c0 + k];
    }
    #pragma unroll
    for (int k=0;k<20;k++) sm[LZ1(c0+k, lane)] = acc[k];
  }
  __syncthreads();

  // ---- stage C: private branch pipeline (wave g) ----
  // L2 forward: z2[40] pre-activation (W2 rows contiguous -> s_load_dwordx16)
  float z2[40];
  #pragma unroll
  for (int o=0;o<40;o++) z2[o] = b2[c2b+o];
  for (int i=0;i<40;i++) {
    const float x1 = __sinf(sm[LZ1(40*h+i, lane)]);
    #pragma unroll
    for (int o=0;o<40;o++) z2[o] += x1 * W2[(40*h+i)*160 + c2b + o];
  }

  float val;
  if (!BND) {
    // s2 = sin(z2) in place; layer 3 column-wise, never materialize z3[80]
    #pragma unroll
    for (int i=0;i<40;i++) z2[i] = __sinf(z2[i]);
    float Gp = (w==0) ? b4[0] : 0.f;
    for (int o=0;o<80;o++) {
      const float* wc = &W3[40*g*320 + 80*g + o];   // column: elem i at wc[i*320]
      float a0=b3[80*g+o], a1=0.f, a2=0.f, a3=0.f;
      #pragma unroll
      for (int i=0;i<40;i+=4) {
        a0 += z2[i+0]*wc[(i+0)*320]; a1 += z2[i+1]*wc[(i+1)*320];
        a2 += z2[i+2]*wc[(i+2)*320]; a3 += z2[i+3]*wc[(i+3)*320];
      }
      Gp += __sinf((a0+a1)+(a2+a3)) * W4[80*g+o];
    }
    const float fx = __sinf(PI_F*cval*in0) * __sinf(PI_F*in1) * __sinf(PI_F*in2);
    val = Gp * fx * xi_wts[p];
  } else {
    // s2 = sin(z2); keep z2 for cos later
    float s2[40];
    #pragma unroll
    for (int i=0;i<40;i++) s2[i] = __sinf(z2[i]);
    // L3 fwd+bwd fused, column-wise: dZ2acc[i] = sum_o W3[i][o] * dz3_o
    float dZ2acc[40];
    #pragma unroll
    for (int i=0;i<40;i++) dZ2acc[i] = 0.f;
    for (int o=0;o<80;o++) {
      const float* wc = &W3[40*g*320 + 80*g + o];
      float a0=b3[80*g+o], a1=0.f, a2=0.f, a3=0.f;
      #pragma unroll
      for (int i=0;i<40;i+=4) {
        a0 += s2[i+0]*wc[(i+0)*320]; a1 += s2[i+1]*wc[(i+1)*320];
        a2 += s2[i+2]*wc[(i+2)*320]; a3 += s2[i+3]*wc[(i+3)*320];
      }
      const float dz3 = __cosf((a0+a1)+(a2+a3)) * W4[80*g+o];
      #pragma unroll
      for (int i=0;i<40;i++) dZ2acc[i] += dz3 * wc[i*320];
    }
    // dZ2 = dZ2acc .* cos(z2)  (kills z2, s2)
    #pragma unroll
    for (int i=0;i<40;i++) z2[i] = dZ2acc[i] * __cosf(z2[i]);
    // L2 backward: dz1[i] = dot(W2 row, dZ2) * cos(Z1half[i])
    float dz1[40];
    #pragma unroll
    for (int i=0;i<40;i++) {
      const float* wr = &W2[(40*h+i)*160 + c2b];
      float a0=0.f,a1=0.f,a2=0.f,a3=0.f;
      #pragma unroll
      for (int o=0;o<40;o+=4) {
        a0 += z2[o+0]*wr[o+0]; a1 += z2[o+1]*wr[o+1];
        a2 += z2[o+2]*wr[o+2]; a3 += z2[o+3]*wr[o+3];
      }
      dz1[i] = ((a0+a1)+(a2+a3)) * __cosf(sm[LZ1(40*h+i, lane)]);
    }
    // L1 backward + fold to x-gradient
    float dx0=0.f, dx1=0.f, dx2=0.f;
    for (int j=0;j<40;j++) {
      const float* wr = &W1[j*80 + 40*h];
      float a0=0.f,a1=0.f,a2=0.f,a3=0.f;
      #pragma unroll
      for (int i=0;i<40;i+=4) {
        a0 += dz1[i+0]*wr[i+0]; a1 += dz1[i+1]*wr[i+1];
        a2 += dz1[i+2]*wr[i+2]; a3 += dz1[i+3]*wr[i+3];
      }
      const float e = ((a0+a1)+(a2+a3)) * __cosf(sm[LZ0(j, lane)]);
      dx0 += e * W0[0*40+j];
      dx1 += e * W0[1*40+j];
      dx2 += e * W0[2*40+j];
    }
    const float n0 = xb_normal[p*3+0], n1 = xb_normal[p*3+1], n2 = xb_normal[p*3+2];
    const float gn = dx0*n0 + dx1*n1 + dx2*n2;
    const float gb = __sinf(cval*(in0+in1+in2)) * (1.f + 0.1f*(float)xb_btype[p]);
    const float ab = 1.f + 0.5f*__cosf(in0);
    val = gn * ab * gb * xb_wts[p];
  }

  // ---- reduce 256 lanes -> 1 atomic per set ----
  #pragma unroll
  for (int off=32; off>0; off>>=1) val += __shfl_down(val, off);
  if (lane==0) sm[LRED + w] = val;
  __syncthreads();
  if (tid==0) {
    const float ssum = sm[LRED+0]+sm[LRED+1]+sm[LRED+2]+sm[LRED+3];
    atomicAdd(out + z, BND ? -ssum : ssum);
  }
}

extern "C" void kernel_launch(void* const* d_in, const int* in_sizes, int n_in,
                              void* d_out, int out_size, void* d_ws, size_t ws_size,
                              hipStream_t stream) {
  const float* xi_coord  = (const float*)d_in[0];
  const float* xi_wts    = (const float*)d_in[1];
  const float* xb_coord  = (const float*)d_in[2];
  const float* xb_wts    = (const float*)d_in[3];
  const float* xb_normal = (const float*)d_in[4];
  const float* z_coord   = (const float*)d_in[5];
  const float* W0 = (const float*)d_in[6];
  const float* b0 = (const float*)d_in[7];
  const float* W1 = (const float*)d_in[8];
  const float* b1 = (const float*)d_in[9];
  const float* W2 = (const float*)d_in[10];
  const float* b2 = (const float*)d_in[11];
  const float* W3 = (const float*)d_in[12];
  const float* b3 = (const float*)d_in[13];
  const float* W4 = (const float*)d_in[14];
  const float* b4 = (const float*)d_in[15];
  const int* xb_btype   = (const int*)d_in[16];
  const int* case_index = (const int*)d_in[17];
  float* out = (float*)d_out;

  hipMemsetAsync(d_out, 0, (size_t)out_size * sizeof(float), stream);

  dim3 grid(4096), blk(256);
  hipLaunchKernelGGL((net_integral<false>), grid, blk, 0, stream,
      xi_coord, xi_wts, xb_coord, xb_wts, xb_normal, z_coord,
      W0, b0, W1, b1, W2, b2, W3, b3, W4, b4, xb_btype, case_index, out);
  hipLaunchKernelGGL((net_integral<true>), grid, blk, 0, stream,
      xi_coord, xi_wts, xb_coord, xb_wts, xb_normal, z_coord,
      W0, b0, W1, b1, W2, b2, W3, b3, W4, b4, xb_btype, case_index, out);
}

// Round 4
// 773.633 us; speedup vs baseline: 9.5535x; 1.2722x over previous
//
#include <hip/hip_runtime.h>

#define PI_F 3.14159265358979f

// LDS float layout: Z0[40][64] | Z1[80][64] | red[4]
#define LZ0(i,pt)  ((i)*64 + (pt))
#define LZ1(c,pt)  (2560 + (c)*64 + (pt))
#define LRED       (2560 + 5120)
#define LDS_FLOATS (2560 + 5120 + 4)

// Pre-transpose the block-diagonal of W3 so layer-3 columns are contiguous:
// W3T[g*3200 + o*40 + i] = W3[(40g+i)*320 + 80g + o],  g<4, o<80, i<40.
__global__ __launch_bounds__(256)
void transpose_w3(const float* __restrict__ W3, float* __restrict__ W3T) {
  const int idx = blockIdx.x * 256 + threadIdx.x;
  if (idx < 12800) {
    const int g = idx / 3200; const int r = idx - g * 3200;
    const int o = r / 40;     const int i = r - o * 40;
    W3T[idx] = W3[(40*g + i)*320 + 80*g + o];
  }
}

// One wave per layer-3 branch (g = wave id, uniform -> weights via s_load),
// one lane per point, one point-set per block. Boundary blocks = bid<4096,
// interior = bid>=4096 (merged so both phases co-schedule). Layer 3 walks
// columns of the PRE-TRANSPOSED W3T: 40 contiguous floats -> wide s_loads,
// reused in SGPRs for fwd dot AND bwd axpy. All register arrays are
// constant-indexed (unrolled inner loops only).
__global__ __launch_bounds__(256)
void net_integral(const float* __restrict__ xi_coord, const float* __restrict__ xi_wts,
                  const float* __restrict__ xb_coord, const float* __restrict__ xb_wts,
                  const float* __restrict__ xb_normal, const float* __restrict__ z_coord,
                  const float* __restrict__ W0, const float* __restrict__ b0,
                  const float* __restrict__ W1, const float* __restrict__ b1,
                  const float* __restrict__ W2, const float* __restrict__ b2,
                  const float* __restrict__ W3T, const float* __restrict__ b3,
                  const float* __restrict__ W4, const float* __restrict__ b4,
                  const int* __restrict__ xb_btype, const int* __restrict__ case_index,
                  float* __restrict__ out)
{
  __shared__ float sm[LDS_FLOATS];
  const int tid  = threadIdx.x;
  const int lane = tid & 63;
  const int w   = __builtin_amdgcn_readfirstlane(tid >> 6);
  const int g   = w;            // layer-3 branch (0..3)
  const int h   = w >> 1;       // layer-2 block / X1 half
  const int c2b = 40*g;         // layer-2 col base

  const int bid = blockIdx.x;
  const bool bnd = (bid < 4096);          // boundary first (longer work)
  const int sidx = bnd ? bid : bid - 4096;
  const int z = sidx >> 3;
  const int p = ((sidx & 7) << 6) + lane;

  const float cval = (float)(case_index[0] + 1);

  const float* xc = bnd ? xb_coord : xi_coord;
  const float in0 = xc[p*3+0], in1 = xc[p*3+1], in2 = xc[p*3+2];
  const float zc0 = z_coord[z*3+0], zc1 = z_coord[z*3+1], zc2 = z_coord[z*3+2];

  // ---- stage A: Z0 pre-activation, wave w -> outputs [10w, 10w+10) ----
  {
    const int ob = 10*w;
    #pragma unroll
    for (int k=0;k<10;k++) {
      float a = b0[ob+k]
        + in0*W0[0*40+ob+k] + in1*W0[1*40+ob+k] + in2*W0[2*40+ob+k]
        + zc0*W0[3*40+ob+k] + zc1*W0[4*40+ob+k] + zc2*W0[5*40+ob+k];
      sm[LZ0(ob+k, lane)] = a;
    }
  }
  __syncthreads();

  // ---- stage B: Z1 pre-activation, wave w -> flat cols [20w, 20w+20) ----
  {
    const int c0 = 20*w;
    float acc[20];
    #pragma unroll
    for (int k=0;k<20;k++) acc[k] = b1[c0+k];
    for (int i=0;i<40;i++) {
      const float x0 = __sinf(sm[LZ0(i,lane)]);
      #pragma unroll
      for (int k=0;k<20;k++) acc[k] += x0 * W1[i*80 + c0 + k];
    }
    #pragma unroll
    for (int k=0;k<20;k++) sm[LZ1(c0+k, lane)] = acc[k];
  }
  __syncthreads();

  // ---- L2 forward: z2[40] pre-activation (W2 rows contiguous -> wide s_load) ----
  float z2[40];
  #pragma unroll
  for (int o=0;o<40;o++) z2[o] = b2[c2b+o];
  for (int i=0;i<40;i++) {
    const float x1 = __sinf(sm[LZ1(40*h+i, lane)]);
    #pragma unroll
    for (int o=0;o<40;o++) z2[o] += x1 * W2[(40*h+i)*160 + c2b + o];
  }

  const float* W3Tg = &W3T[g*3200];   // column o at +o*40, 40 contiguous floats

  float val;
  if (!bnd) {
    // s2 = sin(z2) in place; layer 3 column-wise over contiguous W3T columns
    #pragma unroll
    for (int i=0;i<40;i++) z2[i] = __sinf(z2[i]);
    float Gp = (w==0) ? b4[0] : 0.f;
    for (int o=0;o<80;o++) {
      const float* wc = W3Tg + o*40;
      float a0=b3[80*g+o], a1=0.f, a2=0.f, a3=0.f;
      #pragma unroll
      for (int i=0;i<40;i+=4) {
        a0 += z2[i+0]*wc[i+0]; a1 += z2[i+1]*wc[i+1];
        a2 += z2[i+2]*wc[i+2]; a3 += z2[i+3]*wc[i+3];
      }
      Gp += __sinf((a0+a1)+(a2+a3)) * W4[80*g+o];
    }
    const float fx = __sinf(PI_F*cval*in0) * __sinf(PI_F*in1) * __sinf(PI_F*in2);
    val = Gp * fx * xi_wts[p];
  } else {
    float s2[40];
    #pragma unroll
    for (int i=0;i<40;i++) s2[i] = __sinf(z2[i]);
    float dZ2acc[40];
    #pragma unroll
    for (int i=0;i<40;i++) dZ2acc[i] = 0.f;
    // L3 fwd+bwd fused, column-wise; wc[] SGPR values reused by dot and axpy
    for (int o=0;o<80;o++) {
      const float* wc = W3Tg + o*40;
      float a0=b3[80*g+o], a1=0.f, a2=0.f, a3=0.f;
      #pragma unroll
      for (int i=0;i<40;i+=4) {
        a0 += s2[i+0]*wc[i+0]; a1 += s2[i+1]*wc[i+1];
        a2 += s2[i+2]*wc[i+2]; a3 += s2[i+3]*wc[i+3];
      }
      const float dz3 = __cosf((a0+a1)+(a2+a3)) * W4[80*g+o];
      #pragma unroll
      for (int i=0;i<40;i++) dZ2acc[i] += dz3 * wc[i];
    }
    // dZ2 = dZ2acc .* cos(z2)
    #pragma unroll
    for (int i=0;i<40;i++) z2[i] = dZ2acc[i] * __cosf(z2[i]);
    // L2 backward: dz1[i] = dot(W2 row, dZ2) * cos(Z1half[i])
    float dz1[40];
    #pragma unroll
    for (int i=0;i<40;i++) {
      const float* wr = &W2[(40*h+i)*160 + c2b];
      float a0=0.f,a1=0.f,a2=0.f,a3=0.f;
      #pragma unroll
      for (int o=0;o<40;o+=4) {
        a0 += z2[o+0]*wr[o+0]; a1 += z2[o+1]*wr[o+1];
        a2 += z2[o+2]*wr[o+2]; a3 += z2[o+3]*wr[o+3];
      }
      dz1[i] = ((a0+a1)+(a2+a3)) * __cosf(sm[LZ1(40*h+i, lane)]);
    }
    // L1 backward + fold to x-gradient
    float dx0=0.f, dx1=0.f, dx2=0.f;
    for (int j=0;j<40;j++) {
      const float* wr = &W1[j*80 + 40*h];
      float a0=0.f,a1=0.f,a2=0.f,a3=0.f;
      #pragma unroll
      for (int i=0;i<40;i+=4) {
        a0 += dz1[i+0]*wr[i+0]; a1 += dz1[i+1]*wr[i+1];
        a2 += dz1[i+2]*wr[i+2]; a3 += dz1[i+3]*wr[i+3];
      }
      const float e = ((a0+a1)+(a2+a3)) * __cosf(sm[LZ0(j, lane)]);
      dx0 += e * W0[0*40+j];
      dx1 += e * W0[1*40+j];
      dx2 += e * W0[2*40+j];
    }
    const float n0 = xb_normal[p*3+0], n1 = xb_normal[p*3+1], n2 = xb_normal[p*3+2];
    const float gn = dx0*n0 + dx1*n1 + dx2*n2;
    const float gb = __sinf(cval*(in0+in1+in2)) * (1.f + 0.1f*(float)xb_btype[p]);
    const float ab = 1.f + 0.5f*__cosf(in0);
    val = gn * ab * gb * xb_wts[p];
  }

  // ---- reduce 256 lanes -> 1 atomic per set ----
  #pragma unroll
  for (int off=32; off>0; off>>=1) val += __shfl_down(val, off);
  if (lane==0) sm[LRED + w] = val;
  __syncthreads();
  if (tid==0) {
    const float ssum = sm[LRED+0]+sm[LRED+1]+sm[LRED+2]+sm[LRED+3];
    atomicAdd(out + z, bnd ? -ssum : ssum);
  }
}

extern "C" void kernel_launch(void* const* d_in, const int* in_sizes, int n_in,
                              void* d_out, int out_size, void* d_ws, size_t ws_size,
                              hipStream_t stream) {
  const float* xi_coord  = (const float*)d_in[0];
  const float* xi_wts    = (const float*)d_in[1];
  const float* xb_coord  = (const float*)d_in[2];
  const float* xb_wts    = (const float*)d_in[3];
  const float* xb_normal = (const float*)d_in[4];
  const float* z_coord   = (const float*)d_in[5];
  const float* W0 = (const float*)d_in[6];
  const float* b0 = (const float*)d_in[7];
  const float* W1 = (const float*)d_in[8];
  const float* b1 = (const float*)d_in[9];
  const float* W2 = (const float*)d_in[10];
  const float* b2 = (const float*)d_in[11];
  const float* W3 = (const float*)d_in[12];
  const float* b3 = (const float*)d_in[13];
  const float* W4 = (const float*)d_in[14];
  const float* b4 = (const float*)d_in[15];
  const int* xb_btype   = (const int*)d_in[16];
  const int* case_index = (const int*)d_in[17];
  float* out = (float*)d_out;
  float* W3T = (float*)d_ws;   // 12800 floats = 51200 B

  hipMemsetAsync(d_out, 0, (size_t)out_size * sizeof(float), stream);

  hipLaunchKernelGGL(transpose_w3, dim3(50), dim3(256), 0, stream, W3, W3T);

  hipLaunchKernelGGL(net_integral, dim3(8192), dim3(256), 0, stream,
      xi_coord, xi_wts, xb_coord, xb_wts, xb_normal, z_coord,
      W0, b0, W1, b1, W2, b2, W3T, b3, W4, b4, xb_btype, case_index, out);
}